// Round 1
// baseline (37.696 us; speedup 1.0000x reference)
//
#include <hip/hip_runtime.h>
#include <hip/hip_bf16.h>

// out[b,s,d] = x[b,s,d] * (feature_rand[s] >= 0.2f ? 1 : 0)
// x: (128, 128, 2048) f32, feature_rand: (128,) f32.
// Memory-bound elementwise; float4 vectorized, wave-uniform row branch lets
// dropped rows skip the global read (store zeros only).

#define DROPOUT_PROB 0.2f

__global__ void SpectralDropout_37254546325874_kernel(
    const float4* __restrict__ x,
    const float* __restrict__ feature_rand,
    float4* __restrict__ out,
    int n4)
{
    const int stride = gridDim.x * blockDim.x;
    for (int i = blockIdx.x * blockDim.x + threadIdx.x; i < n4; i += stride) {
        // 2048 floats per row = 512 float4 per row; 128 rows (s) per batch.
        const int s = (i >> 9) & 127;
        // Wave-uniform: 64 consecutive lanes stay within one 512-float4 row.
        const bool keep = feature_rand[s] >= DROPOUT_PROB;
        if (keep) {
            out[i] = x[i];
        } else {
            out[i] = make_float4(0.0f, 0.0f, 0.0f, 0.0f);
        }
    }
}

extern "C" void kernel_launch(void* const* d_in, const int* in_sizes, int n_in,
                              void* d_out, int out_size, void* d_ws, size_t ws_size,
                              hipStream_t stream) {
    const float4* x = (const float4*)d_in[0];
    const float* feature_rand = (const float*)d_in[1];
    float4* out = (float4*)d_out;

    const int n4 = out_size / 4;  // 33554432 / 4 = 8388608 float4s

    const int block = 256;
    const int grid = 2048;  // grid-stride; ~16 float4 per thread
    SpectralDropout_37254546325874_kernel<<<grid, block, 0, stream>>>(
        x, feature_rand, out, n4);
}